// Round 1
// baseline (116.759 us; speedup 1.0000x reference)
//
#include <hip/hip_runtime.h>

#define N_MOLS   32768
#define NATOMS   4194304
#define BLOCK    256
#define APT      4                 // atoms per thread
#define APB      (BLOCK * APT)     // atoms per block = 1024
#define NBINS    1088              // local segment bins (block spans ~10 ids typically)

__device__ __forceinline__ void add_seg(float* bins, float* energy,
                                        int first_id, int id, float v) {
    int local = id - first_id;
    if (local < NBINS) {
        atomicAdd(&bins[local], v);        // LDS atomic (ds_add_f32)
    } else {
        atomicAdd(&energy[id], v);         // robustness fallback (never hit w/ this data)
    }
}

__global__ __launch_bounds__(BLOCK)
void SumPool_5325759447404_kernel(const float* __restrict__ xyz,
                                  const int*   __restrict__ seg,
                                  const float* __restrict__ w,
                                  float* __restrict__ energy,
                                  float* __restrict__ grad) {
    __shared__ float bins[NBINS];
    const int block_start = blockIdx.x * APB;

    for (int i = threadIdx.x; i < NBINS; i += BLOCK) bins[i] = 0.0f;

    const float w0 = w[0], w1 = w[1], w2 = w[2];
    const int first_id = seg[block_start];
    __syncthreads();

    const int a0 = block_start + threadIdx.x * APT;

    // 4 atoms = 12 floats = 3 float4 (aligned: a0*3*4 bytes, a0 % 4 == 0)
    const float4* __restrict__ xyz4 = (const float4*)(xyz + (size_t)a0 * 3);
    const float4 p = xyz4[0];
    const float4 q = xyz4[1];
    const float4 r = xyz4[2];

    const float s0 = p.x * w0 + p.y * w1 + p.z * w2;
    const float s1 = p.w * w0 + q.x * w1 + q.y * w2;
    const float s2 = q.z * w0 + q.w * w1 + r.x * w2;
    const float s3 = r.y * w0 + r.z * w1 + r.w * w2;

    const float t0 = tanhf(s0);
    const float t1 = tanhf(s1);
    const float t2 = tanhf(s2);
    const float t3 = tanhf(s3);

    const float d0 = 1.0f - t0 * t0;
    const float d1 = 1.0f - t1 * t1;
    const float d2 = 1.0f - t2 * t2;
    const float d3 = 1.0f - t3 * t3;

    float4 g0, g1, g2;
    g0.x = d0 * w0; g0.y = d0 * w1; g0.z = d0 * w2; g0.w = d1 * w0;
    g1.x = d1 * w1; g1.y = d1 * w2; g1.z = d2 * w0; g1.w = d2 * w1;
    g2.x = d2 * w2; g2.y = d3 * w0; g2.z = d3 * w1; g2.w = d3 * w2;

    float4* __restrict__ grad4 = (float4*)(grad + (size_t)a0 * 3);
    grad4[0] = g0;
    grad4[1] = g1;
    grad4[2] = g2;

    const int4 ids = *(const int4*)(seg + a0);

    // run-merge consecutive equal ids (sorted), then LDS-binned atomic
    float acc = t0;
    int   cur = ids.x;
    if (ids.y == cur) { acc += t1; } else { add_seg(bins, energy, first_id, cur, acc); cur = ids.y; acc = t1; }
    if (ids.z == cur) { acc += t2; } else { add_seg(bins, energy, first_id, cur, acc); cur = ids.z; acc = t2; }
    if (ids.w == cur) { acc += t3; } else { add_seg(bins, energy, first_id, cur, acc); cur = ids.w; acc = t3; }
    add_seg(bins, energy, first_id, cur, acc);

    __syncthreads();

    // flush the block's bins: range of ids actually spanned by this block
    const int last_id = seg[block_start + APB - 1];
    int range = last_id - first_id + 1;
    if (range > NBINS) range = NBINS;
    for (int i = threadIdx.x; i < range; i += BLOCK) {
        const float v = bins[i];
        if (v != 0.0f) atomicAdd(&energy[first_id + i], v);
    }
}

extern "C" void kernel_launch(void* const* d_in, const int* in_sizes, int n_in,
                              void* d_out, int out_size, void* d_ws, size_t ws_size,
                              hipStream_t stream) {
    const float* xyz = (const float*)d_in[0];
    const int*   seg = (const int*)d_in[1];
    const float* w   = (const float*)d_in[2];

    float* energy = (float*)d_out;            // [N_MOLS]
    float* grad   = energy + N_MOLS;          // [NATOMS * 3]

    // energy is accumulated with atomics — must start at zero (d_out is poisoned)
    hipMemsetAsync(d_out, 0, N_MOLS * sizeof(float), stream);

    const int nblocks = NATOMS / APB;         // 4096, exact
    SumPool_5325759447404_kernel<<<nblocks, BLOCK, 0, stream>>>(xyz, seg, w, energy, grad);
}